// Round 11
// baseline (196.382 us; speedup 1.0000x reference)
//
#include <hip/hip_runtime.h>
#include <hip/hip_bf16.h>

#define N_ATOMS 32768

typedef __attribute__((ext_vector_type(4))) float f32x4;
typedef __attribute__((ext_vector_type(8))) short bf16x8;
typedef unsigned short u16;

__device__ __forceinline__ u16 f2b(float f) {
    union { __hip_bfloat16 b; u16 u; } c;
    c.b = __float2bfloat16(f);
    return c.u;
}
__device__ __forceinline__ float b2f(u16 u) {
    union { unsigned int i; float f; } c;
    c.i = ((unsigned int)u) << 16;
    return c.f;
}

#define GLDS16(src, dst) __builtin_amdgcn_global_load_lds( \
    (const __attribute__((address_space(1))) void*)(src),  \
    (__attribute__((address_space(3))) void*)(dst), 16, 0, 0)

// ---------------- merged setup kernel: convx + convw + zero(out_inv) ----------------
__global__ void __launch_bounds__(256) setup_kernel(
        const float* __restrict__ x, u16* __restrict__ xhi, u16* __restrict__ xlo,
        const float* __restrict__ w1l, const float* __restrict__ w2l,
        const float* __restrict__ w3l, const float* __restrict__ w1r,
        const float* __restrict__ w2r,
        u16* __restrict__ W1LThi, u16* __restrict__ W1LTlo, u16* __restrict__ W1RT,
        u16* __restrict__ W2LThi, u16* __restrict__ W2LTlo, u16* __restrict__ W2RT,
        u16* __restrict__ W3LThi, u16* __restrict__ W3LTlo,
        float* __restrict__ out_inv) {
    int bid = blockIdx.x;
    if (bid < 4096) {
        size_t i = (size_t)(bid * 256 + threadIdx.x) * 8;
        float4 v0 = *(const float4*)(x + i);
        float4 v1 = *(const float4*)(x + i + 4);
        float v[8] = {v0.x, v0.y, v0.z, v0.w, v1.x, v1.y, v1.z, v1.w};
        bf16x8 rh, rl;
#pragma unroll
        for (int j = 0; j < 8; ++j) {
            u16 h = f2b(v[j]);
            rh[j] = (short)h;
            rl[j] = (short)f2b(v[j] - b2f(h));
        }
        *(bf16x8*)(xhi + i) = rh;
        *(bf16x8*)(xlo + i) = rl;
    } else if (bid < 7424) {
        int i = (bid - 4096) * 256 + threadIdx.x;
        if (i < 131072) {                       // w1_lat -> [512][256] hi/lo
            int n = i >> 8, k = i & 255;
            float v = w1l[k * 512 + n];
            u16 h = f2b(v);
            W1LThi[i] = h;
            W1LTlo[i] = f2b(v - b2f(h));
        } else if (i < 262144) {                // w1_ro -> [512][256] bf16
            int j = i - 131072;
            int n = j >> 8, k = j & 255;
            W1RT[j] = f2b(w1r[k * 512 + n]);
        } else if (i < 524288) {                // w2_lat -> [512][512] hi/lo
            int j = i - 262144;
            int n = j >> 9, k = j & 511;
            float v = w2l[k * 512 + n];
            u16 h = f2b(v);
            W2LThi[j] = h;
            W2LTlo[j] = f2b(v - b2f(h));
        } else if (i < 786432) {                // w2_ro -> bf16
            int j = i - 524288;
            int n = j >> 9, k = j & 511;
            W2RT[j] = f2b(w2r[k * 512 + n]);
        } else if (i < 851968) {                // w3_lat -> [128][512] hi/lo
            int j = i - 786432;
            int n = j >> 9, k = j & 511;
            float v = w3l[k * 128 + n];
            u16 h = f2b(v);
            W3LThi[j] = h;
            W3LTlo[j] = f2b(v - b2f(h));
        }
    } else {
        int i = (bid - 7424) * 256 + threadIdx.x;
        *(float4*)(out_inv + i * 4) = float4{0.f, 0.f, 0.f, 0.f};
    }
}

// ---------------- gemm4p: 4-phase counted-vmcnt split-bf16 GEMM (lat branch) ----------------
// C = silu( scale * (Ahi@Bhi^T + Alo@Bhi^T + Ahi@Blo^T) ), split hi/lo bf16 out.
// BM=256, BN=256, BK=64, 512 threads = 8 waves (2M x 4N), per-wave 128x64.
// LDS: 2 K-tile buffers, each split into two K-HALVES (256 rows x 32 cols, 16KB).
// Per tile, 4 phases q=(ks,mh): q0/q1 read K-half0, q2/q3 K-half1; 16 MFMA each.
// Stage 1 half-tile/phase: tile t+1's half q into buf[t&1^1] (slot's last reader
// finished at previous tile boundary).  Waits: vmcnt(4) before q0 and before q2
// (outstanding=8, oldest 4 loads = exactly the two halves the next phases read);
// cover per half >= 3 phases (~1500cyc > HBM 900).  NO vmcnt(0) in the loop.
// Swizzle for 64B rows: chunk c = cp ^ ((row>>1)&3) -> 2-way bank alias (free);
// stage dest row*32+cp*8 u16 is lane*16B-linear per wave (gload_lds legal).
template<int GX>
__global__ void __launch_bounds__(512, 1) gemm4p(
        const u16* __restrict__ Ahi, const u16* __restrict__ Alo,
        const u16* __restrict__ Bhi, const u16* __restrict__ Blo,
        u16* __restrict__ Chi, u16* __restrict__ Clo,
        int ldc, int K, float scale) {
    __shared__ __align__(16) u16 smem[65536];   // 128 KB
    u16* const lA0 = smem;                      // [2 buf][2 khalf][256*32]
    u16* const lB0 = smem + 32768;
    const int tid = threadIdx.x;
    const int lane = tid & 63;
    const int wid = tid >> 6;
    const int wm = wid >> 2;            // 0..1
    const int wn = wid & 3;             // 0..3
    const int rlane = lane & 15;
    const int kc = lane >> 4;           // 0..3 (8-col chunk within 32-col K-half)
    const int srow0 = tid >> 2;         // 0..127 (staging row base)
    const int scp = tid & 3;            // staging chunk

    const int nwg = gridDim.x;
    const int bid = blockIdx.x;
    const int wg = (bid & 7) * (nwg >> 3) + (bid >> 3);
    const int bn = (wg % GX) * 256;
    const int bm = (wg / GX) * 256;

    const int kt = K >> 6;
    const int NT = 3 * kt;

    auto stageA = [&](int t, int buf, int kh) {
        int seg = (t >= kt) + (t >= 2 * kt);
        const u16* As = (seg == 1) ? Alo : Ahi;
        int k0 = (t - seg * kt) * 64 + kh * 32;
        u16* la = lA0 + buf * 16384 + kh * 8192;
#pragma unroll
        for (int call = 0; call < 2; ++call) {
            int row = call * 128 + srow0;
            int c = scp ^ ((row >> 1) & 3);
            GLDS16(As + (size_t)(bm + row) * K + k0 + c * 8, la + row * 32 + scp * 8);
        }
    };
    auto stageB = [&](int t, int buf, int kh) {
        int seg = (t >= kt) + (t >= 2 * kt);
        const u16* Bs = (seg == 2) ? Blo : Bhi;
        int k0 = (t - seg * kt) * 64 + kh * 32;
        u16* lb = lB0 + buf * 16384 + kh * 8192;
#pragma unroll
        for (int call = 0; call < 2; ++call) {
            int row = call * 128 + srow0;
            int c = scp ^ ((row >> 1) & 3);
            GLDS16(Bs + (size_t)(bn + row) * K + k0 + c * 8, lb + row * 32 + scp * 8);
        }
    };

    f32x4 acc[8][4] = {};
    bf16x8 af[4], bf[4];

#define RD_A(buf, kh, mh) do {                                                \
        const u16* la_ = lA0 + (buf) * 16384 + (kh) * 8192;                   \
        _Pragma("unroll")                                                     \
        for (int m_ = 0; m_ < 4; ++m_) {                                      \
            int row_ = wm * 128 + (mh) * 64 + m_ * 16 + rlane;                \
            int c_ = kc ^ ((row_ >> 1) & 3);                                  \
            af[m_] = *(const bf16x8*)&la_[row_ * 32 + c_ * 8];                \
        }                                                                     \
    } while (0)
#define RD_B(buf, kh) do {                                                    \
        const u16* lb_ = lB0 + (buf) * 16384 + (kh) * 8192;                   \
        _Pragma("unroll")                                                     \
        for (int n_ = 0; n_ < 4; ++n_) {                                      \
            int row_ = wn * 64 + n_ * 16 + rlane;                             \
            int c_ = kc ^ ((row_ >> 1) & 3);                                  \
            bf[n_] = *(const bf16x8*)&lb_[row_ * 32 + c_ * 8];                \
        }                                                                     \
    } while (0)
#define LGKM0 do {                                                            \
        asm volatile("s_waitcnt lgkmcnt(0)" ::: "memory");                    \
        __builtin_amdgcn_sched_barrier(0);                                    \
    } while (0)
#define MM(mh) do {                                                           \
        __builtin_amdgcn_s_setprio(1);                                        \
        _Pragma("unroll")                                                     \
        for (int m_ = 0; m_ < 4; ++m_)                                        \
            _Pragma("unroll")                                                 \
            for (int n_ = 0; n_ < 4; ++n_)                                    \
                acc[(mh) * 4 + m_][n_] = __builtin_amdgcn_mfma_f32_16x16x32_bf16( \
                    af[m_], bf[n_], acc[(mh) * 4 + m_][n_], 0, 0, 0);         \
        __builtin_amdgcn_s_setprio(0);                                        \
    } while (0)

    // prologue: tile 0's four K-half-tiles (order A0,B0,A1,B1), 8 loads/thread
    stageA(0, 0, 0);
    stageB(0, 0, 0);
    stageA(0, 0, 1);
    stageB(0, 0, 1);

    for (int t = 0; t < NT; ++t) {
        const int cur = t & 1, oth = cur ^ 1;
        const bool pf = (t + 1 < NT);
        // W1: A0,B0(t) are the oldest 4 outstanding loads -> landed after vmcnt(4)
        asm volatile("s_waitcnt vmcnt(4)" ::: "memory");
        __builtin_amdgcn_s_barrier();
        // q0: ks=0, mh=0
        RD_B(cur, 0);
        RD_A(cur, 0, 0);
        if (pf) stageA(t + 1, oth, 0);
        LGKM0;
        MM(0);
        // q1: ks=0, mh=1 (bf reuse)
        RD_A(cur, 0, 1);
        if (pf) stageB(t + 1, oth, 0);
        LGKM0;
        MM(1);
        // W2: A1,B1(t) landed (all but 4 newest; last tile: drain)
        if (pf) asm volatile("s_waitcnt vmcnt(4)" ::: "memory");
        else    asm volatile("s_waitcnt vmcnt(0)" ::: "memory");
        __builtin_amdgcn_s_barrier();
        // q2: ks=1, mh=0
        RD_B(cur, 1);
        RD_A(cur, 1, 0);
        if (pf) stageA(t + 1, oth, 1);
        LGKM0;
        MM(0);
        // q3: ks=1, mh=1
        RD_A(cur, 1, 1);
        if (pf) stageB(t + 1, oth, 1);
        LGKM0;
        MM(1);
    }
#undef MM
#undef LGKM0
#undef RD_B
#undef RD_A

    // epilogue: split hi/lo bf16 out.  acc index M <-> row M*16 (same as gemm8p).
    const int g = lane >> 4;
#pragma unroll
    for (int m = 0; m < 8; ++m) {
        int grow0 = bm + wm * 128 + m * 16 + (g << 2);
#pragma unroll
        for (int n = 0; n < 4; ++n) {
            int gcol = bn + wn * 64 + n * 16 + rlane;
#pragma unroll
            for (int r = 0; r < 4; ++r) {
                float v = acc[m][n][r] * scale;
                v = v / (1.0f + __expf(-v));
                size_t idx = (size_t)(grow0 + r) * ldc + gcol;
                u16 h = f2b(v);
                Chi[idx] = h;
                Clo[idx] = f2b(v - b2f(h));
            }
        }
    }
}

// ---------------- 256-row 8-wave MFMA GEMM (R4/R7/R9-proven schedule) ----------------
// OUTK: 0 = f32, 1 = bf16, 3 = fused invout (dot w3_ro -> atomicAdd e_out).
template<int NSEG, int GX, int NF, bool SILU, int OUTK>
__global__ void __launch_bounds__(512, 2) gemm8p(
        const u16* __restrict__ Ahi, const u16* __restrict__ Alo,
        const u16* __restrict__ Bhi, const u16* __restrict__ Blo,
        void* __restrict__ Chi, void* __restrict__ Clo,
        int ldc, int K, float scale,
        const float* __restrict__ e_w3, float* __restrict__ e_out) {
    constexpr int LBSZ = NF * 64 * 64;
    constexpr int SMEMN = 32768 + 2 * LBSZ;
    __shared__ __align__(16) u16 smem[SMEMN];
    u16* const lA0 = smem;
    u16* const lB0 = smem + 32768;
    const int tid = threadIdx.x;
    const int lane = tid & 63;
    const int wid = tid >> 6;
    const int wm = wid >> 2;
    const int wn = wid & 3;
    const int rlane = lane & 15;
    const int kc = lane >> 4;
    const int cps = rlane & 7;
    const int srow = tid >> 3;
    const int scp = tid & 7;

    const int nwg = gridDim.x;
    const int bid = blockIdx.x;
    const int wg = (bid & 7) * (nwg >> 3) + (bid >> 3);
    const int bn = (wg % GX) * (NF * 64);
    const int bm = (wg / GX) * 256;

    const int kt = K >> 6;
    const int NT = NSEG * kt;

    auto stageA = [&](int t, int buf) {
        int seg = (NSEG == 1) ? 0 : ((t >= kt) + (t >= 2 * kt));
        const u16* As = (NSEG == 1) ? Ahi : (seg == 1 ? Alo : Ahi);
        int k0 = (t - seg * kt) << 6;
        u16* la = lA0 + buf * 16384;
#pragma unroll
        for (int call = 0; call < 4; ++call) {
            int row = call * 64 + srow;
            int c = scp ^ (row & 7);
            GLDS16(As + (size_t)(bm + row) * K + k0 + c * 8, la + (size_t)(row * 64 + scp * 8));
        }
    };
    auto stageB = [&](int t, int buf) {
        int seg = (NSEG == 1) ? 0 : ((t >= kt) + (t >= 2 * kt));
        const u16* Bs = (NSEG == 1) ? Bhi : (seg == 2 ? Blo : Bhi);
        int k0 = (t - seg * kt) << 6;
        u16* lb = lB0 + buf * LBSZ;
#pragma unroll
        for (int call = 0; call < NF; ++call) {
            int row = call * 64 + srow;
            int c = scp ^ (row & 7);
            GLDS16(Bs + (size_t)(bn + row) * K + k0 + c * 8, lb + (size_t)(row * 64 + scp * 8));
        }
    };

    f32x4 acc[8][NF] = {};

    stageA(0, 0);
    stageB(0, 0);
    asm volatile("s_waitcnt vmcnt(0)" ::: "memory");
    __builtin_amdgcn_s_barrier();

    for (int t = 0; t < NT; ++t) {
        const int cur = t & 1, nxt = cur ^ 1;
        const bool pf = (t + 1 < NT);
        const u16* la = lA0 + cur * 16384;
        const u16* lb = lB0 + cur * LBSZ;
#pragma unroll
        for (int ks = 0; ks < 2; ++ks) {
            bf16x8 af[8], bfr[NF];
            const int cp = (ks * 4 + kc) ^ cps;
#pragma unroll
            for (int m = 0; m < 8; ++m) {
                int row = wm * 128 + m * 16 + rlane;
                af[m] = *(const bf16x8*)&la[row * 64 + cp * 8];
            }
#pragma unroll
            for (int n = 0; n < NF; ++n) {
                int row = wn * (NF * 16) + n * 16 + rlane;
                bfr[n] = *(const bf16x8*)&lb[row * 64 + cp * 8];
            }
            if (pf) {
                if (ks == 0) stageA(t + 1, nxt);
                else         stageB(t + 1, nxt);
            }
            asm volatile("s_waitcnt lgkmcnt(0)" ::: "memory");
            __builtin_amdgcn_sched_barrier(0);
            __builtin_amdgcn_s_setprio(1);
#pragma unroll
            for (int m = 0; m < 8; ++m)
#pragma unroll
                for (int n = 0; n < NF; ++n)
                    acc[m][n] = __builtin_amdgcn_mfma_f32_16x16x32_bf16(af[m], bfr[n], acc[m][n], 0, 0, 0);
            __builtin_amdgcn_s_setprio(0);
        }
        asm volatile("s_waitcnt vmcnt(0)" ::: "memory");
        __builtin_amdgcn_s_barrier();
    }

    const int g = lane >> 4;

    if constexpr (OUTK == 3) {
        const float s512f = 0.04419417382415922f;
        float wj0[NF], wj1[NF];
#pragma unroll
        for (int n = 0; n < NF; ++n) {
            int gc = bn + wn * (NF * 16) + n * 16 + rlane;
            wj0[n] = e_w3[gc * 2] * s512f;
            wj1[n] = e_w3[gc * 2 + 1] * s512f;
        }
#pragma unroll
        for (int m = 0; m < 8; ++m)
#pragma unroll
            for (int r = 0; r < 4; ++r) {
                float s0 = 0.f, s1 = 0.f;
#pragma unroll
                for (int n = 0; n < NF; ++n) {
                    float v = acc[m][n][r] * scale;
                    v = v / (1.0f + __expf(-v));
                    s0 = fmaf(v, wj0[n], s0);
                    s1 = fmaf(v, wj1[n], s1);
                }
#pragma unroll
                for (int off = 1; off < 16; off <<= 1) {
                    s0 += __shfl_xor(s0, off);
                    s1 += __shfl_xor(s1, off);
                }
                if (rlane == 0) {
                    int row = bm + wm * 128 + m * 16 + g * 4 + r;
                    atomicAdd(&e_out[row * 2], s0);
                    atomicAdd(&e_out[row * 2 + 1], s1);
                }
            }
    } else {
#pragma unroll
        for (int m = 0; m < 8; ++m) {
            int grow0 = bm + wm * 128 + m * 16 + (g << 2);
#pragma unroll
            for (int n = 0; n < NF; ++n) {
                int gcol = bn + wn * (NF * 16) + n * 16 + rlane;
#pragma unroll
                for (int r = 0; r < 4; ++r) {
                    float v = acc[m][n][r] * scale;
                    if constexpr (SILU) v = v / (1.0f + __expf(-v));
                    size_t idx = (size_t)(grow0 + r) * ldc + gcol;
                    if constexpr (OUTK == 0) ((float*)Chi)[idx] = v;
                    else                     ((u16*)Chi)[idx] = f2b(v);
                }
            }
        }
    }
}

// ---------------- per-atom equivariant output (R2-verified) ----------------
__global__ void eq_kernel(const float* __restrict__ eqf, const float* __restrict__ wgt,
                          const int* __restrict__ types, const float* __restrict__ bond,
                          float* __restrict__ out) {
    int t = blockIdx.x * 256 + threadIdx.x;
    int n = t >> 2, v = t & 3;
    const float* e = eqf + (size_t)n * 96;
    const float* w = wgt + (size_t)n * 128 + v;
    float a0 = 0.f, a1 = 0.f, a2 = 0.f;
#pragma unroll
    for (int u = 0; u < 32; ++u) {
        float wv = w[u * 4];
        a0 = fmaf(e[u * 3 + 0], wv, a0);
        a1 = fmaf(e[u * 3 + 1], wv, a1);
        a2 = fmaf(e[u * 3 + 2], wv, a2);
    }
    const float s = 0.17677669529663687f;
    a0 *= s; a1 *= s; a2 *= s;
    float norm = sqrtf(a0 * a0 + a1 * a1 + a2 * a2) + 1e-10f;
    float bl = bond[types[n] * 4 + v];
    float r0 = a0 / norm, r1 = a1 / norm, r2 = a2 / norm;
    if (isnan(r0)) r0 = 0.f;
    if (isnan(r1)) r1 = 0.f;
    if (isnan(r2)) r2 = 0.f;
    out[(size_t)n * 12 + v * 3 + 0] = r0 * bl;
    out[(size_t)n * 12 + v * 3 + 1] = r1 * bl;
    out[(size_t)n * 12 + v * 3 + 2] = r2 * bl;
}

// ---------------- launcher ----------------
extern "C" void kernel_launch(void* const* d_in, const int* in_sizes, int n_in,
                              void* d_out, int out_size, void* d_ws, size_t ws_size,
                              hipStream_t stream) {
    const float* inv  = (const float*)d_in[0];
    const float* eqf  = (const float*)d_in[1];
    const int*   typs = (const int*)d_in[2];
    const float* w1l  = (const float*)d_in[3];
    const float* w2l  = (const float*)d_in[4];
    const float* w3l  = (const float*)d_in[5];
    const float* w1r  = (const float*)d_in[6];
    const float* w2r  = (const float*)d_in[7];
    const float* w3r  = (const float*)d_in[8];
    const float* bond = (const float*)d_in[9];

    char* ws = (char*)d_ws;
    const size_t MB = 1024 * 1024, KB = 1024;
    u16* XHI   = (u16*)(ws);             // 16MB, dead after ro-L1
    u16* XLO   = (u16*)(ws + 16 * MB);   // 16MB, dead after lat-L1
    u16* H1R   = (u16*)(ws + 32 * MB);   // 32MB, dead after ro-L2f
    u16* H1Lhi = (u16*)(ws + 64 * MB);   // 32MB, dead after lat-L2
    u16* H1Llo = (u16*)(ws + 96 * MB);   // 32MB, dead after lat-L2
    u16* H2Lhi = (u16*)(ws);             // 32MB, over XHI+XLO (dead)
    u16* H2Llo = (u16*)(ws + 128 * MB);  // 32MB fresh
    float* WGT = (float*)(ws + 32 * MB); // 16MB, over H1R (dead)
    char* wb = ws + 160 * MB;
    u16* W1LThi = (u16*)(wb);
    u16* W1LTlo = (u16*)(wb + 256 * KB);
    u16* W1RT   = (u16*)(wb + 512 * KB);
    u16* W2LThi = (u16*)(wb + 768 * KB);
    u16* W2LTlo = (u16*)(wb + 1280 * KB);
    u16* W2RT   = (u16*)(wb + 1792 * KB);
    u16* W3LThi = (u16*)(wb + 2304 * KB);
    u16* W3LTlo = (u16*)(wb + 2432 * KB);

    float* out_inv = (float*)d_out;                 // [32768][2]
    float* out_eq  = (float*)d_out + N_ATOMS * 2;   // [32768][4][3]

    const float s256 = 0.0625f;                 // 1/sqrt(256)
    const float s512 = 0.04419417382415922f;    // 1/sqrt(512)

    // 1. setup: convx + convw + zero(out_inv)
    setup_kernel<<<dim3(7488), dim3(256), 0, stream>>>(
        inv, XHI, XLO, w1l, w2l, w3l, w1r, w2r,
        W1LThi, W1LTlo, W1RT, W2LThi, W2LTlo, W2RT, W3LThi, W3LTlo, out_inv);
    // 2. lat L1 (4-phase counted-vmcnt split GEMM): -> H1L hi/lo
    gemm4p<2><<<dim3(256), dim3(512), 0, stream>>>(
        XHI, XLO, W1LThi, W1LTlo, H1Lhi, H1Llo, 512, 256, s256);
    // 3. ro L1 (proven gemm8p): -> H1R
    gemm8p<1, 2, 4, true, 1><<<dim3(256), dim3(512), 0, stream>>>(
        XHI, nullptr, W1RT, nullptr, H1R, nullptr, 512, 256, s256, nullptr, nullptr);
    // 4. ro L2 + invout fused (proven gemm8p): atomics into out_inv
    gemm8p<1, 2, 4, true, 3><<<dim3(256), dim3(512), 0, stream>>>(
        H1R, nullptr, W2RT, nullptr, nullptr, nullptr, 0, 512, s512, w3r, out_inv);
    // 5. lat L2 (4-phase counted-vmcnt split GEMM): -> H2L hi/lo
    gemm4p<2><<<dim3(256), dim3(512), 0, stream>>>(
        H1Lhi, H1Llo, W2LThi, W2LTlo, H2Lhi, H2Llo, 512, 512, s512);
    // 6. lat L3 (proven gemm8p, NF=1, full GPU): -> WGT f32
    gemm8p<3, 2, 1, false, 0><<<dim3(256), dim3(512), 0, stream>>>(
        H2Lhi, H2Llo, W3LThi, W3LTlo, WGT, nullptr, 128, 512, s512, nullptr, nullptr);
    // 7. equivariant epilogue
    eq_kernel<<<dim3(512), dim3(256), 0, stream>>>(eqf, WGT, typs, bond, out_eq);
}